// Round 16
// baseline (1113.087 us; speedup 1.0000x reference)
//
#include <hip/hip_runtime.h>
#include <hip/hip_bf16.h>
#include <hip/hip_cooperative_groups.h>
#include <math.h>

namespace cg = cooperative_groups;

// ---------------------------------------------------------------------------
// ActorGNN: 4-layer GraphConv. R16: single cooperative mega-kernel.
//  - R15 accounting: ~265us kernel work vs 405us total -> ~130us of
//    inter-dispatch overhead (10 serial dispatches x ~12us). All phases now
//    run in ONE hipLaunchCooperativeKernel with grid.sync() between (9 syncs
//    at ~2-4us each). Grid-stride everywhere; grid = occupancy x CUs.
//  - dense streams B-frags from L1/L2 (R12 form, VGPR~28) so the kernel
//    stays at 8 blocks/CU and gather keeps 32 waves/CU.
//  - binA capped at min(grid,256) blocks (write-run locality); one 8KB
//    shared buffer unioned across binA/bucketCSR phases.
// ---------------------------------------------------------------------------

using bfrag = __attribute__((ext_vector_type(8))) short;   // 8 bf16 (4 VGPR)
using ffrag = __attribute__((ext_vector_type(4))) float;   // 4 fp32 acc

#define BKT_SHIFT 7                 // 128 nodes per bucket
#define BKT_NODES (1 << BKT_SHIFT)
#define BINB 256                    // max binA blocks

__device__ __forceinline__ int load_idx32(const int* __restrict__ ei32, int is64,
                                          long long pos) {
    return is64 ? ei32[2 * pos] : ei32[pos];
}

__device__ __forceinline__ unsigned short f2b_rne(float f) {
    union { float f; unsigned u; } c;
    c.f = f;
    unsigned r = c.u + 0x7FFFu + ((c.u >> 16) & 1u);
    return (unsigned short)(r >> 16);
}

__device__ __forceinline__ float b2f(unsigned short u) {
    union { unsigned u; float f; } c;
    c.u = ((unsigned)u) << 16;
    return c.f;
}

// ---- gather phase: wave-per-node grid-stride; bf16 rows -> Ghi ----
__device__ __forceinline__ void gather_phase(
    const unsigned short* __restrict__ hb, const int* __restrict__ off,
    const int* __restrict__ offe, const int* __restrict__ col,
    const float* __restrict__ dinv, unsigned short* __restrict__ ghi,
    int N, int wid, int nw, int g, int t) {
    for (int n = wid; n < N; n += nw) {
        int e = off[n], end = offe[n];
        float4 a0 = make_float4(0.f, 0.f, 0.f, 0.f);
        float4 a1 = make_float4(0.f, 0.f, 0.f, 0.f);
        float4 a2 = make_float4(0.f, 0.f, 0.f, 0.f);
        float4 a3 = make_float4(0.f, 0.f, 0.f, 0.f);
        for (; e + 16 <= end; e += 16) {
            int s0 = col[e + g];
            int s1 = col[e + 4 + g];
            int s2 = col[e + 8 + g];
            int s3 = col[e + 12 + g];
            ushort4 u0 = *(const ushort4*)&hb[(size_t)s0 * 64 + t * 4];
            ushort4 u1 = *(const ushort4*)&hb[(size_t)s1 * 64 + t * 4];
            ushort4 u2 = *(const ushort4*)&hb[(size_t)s2 * 64 + t * 4];
            ushort4 u3 = *(const ushort4*)&hb[(size_t)s3 * 64 + t * 4];
            a0.x += b2f(u0.x); a0.y += b2f(u0.y); a0.z += b2f(u0.z); a0.w += b2f(u0.w);
            a1.x += b2f(u1.x); a1.y += b2f(u1.y); a1.z += b2f(u1.z); a1.w += b2f(u1.w);
            a2.x += b2f(u2.x); a2.y += b2f(u2.y); a2.z += b2f(u2.z); a2.w += b2f(u2.w);
            a3.x += b2f(u3.x); a3.y += b2f(u3.y); a3.z += b2f(u3.z); a3.w += b2f(u3.w);
        }
        for (; e + 8 <= end; e += 8) {
            int s0 = col[e + g];
            int s1 = col[e + 4 + g];
            ushort4 u0 = *(const ushort4*)&hb[(size_t)s0 * 64 + t * 4];
            ushort4 u1 = *(const ushort4*)&hb[(size_t)s1 * 64 + t * 4];
            a0.x += b2f(u0.x); a0.y += b2f(u0.y); a0.z += b2f(u0.z); a0.w += b2f(u0.w);
            a1.x += b2f(u1.x); a1.y += b2f(u1.y); a1.z += b2f(u1.z); a1.w += b2f(u1.w);
        }
        for (; e < end; e += 4) {
            if (e + g < end) {
                int s0 = col[e + g];
                ushort4 u0 = *(const ushort4*)&hb[(size_t)s0 * 64 + t * 4];
                a2.x += b2f(u0.x); a2.y += b2f(u0.y); a2.z += b2f(u0.z); a2.w += b2f(u0.w);
            }
        }
        float4 acc;
        acc.x = (a0.x + a1.x) + (a2.x + a3.x);
        acc.y = (a0.y + a1.y) + (a2.y + a3.y);
        acc.z = (a0.z + a1.z) + (a2.z + a3.z);
        acc.w = (a0.w + a1.w) + (a2.w + a3.w);
#pragma unroll
        for (int m = 16; m <= 32; m <<= 1) {
            acc.x += __shfl_xor(acc.x, m, 64);
            acc.y += __shfl_xor(acc.y, m, 64);
            acc.z += __shfl_xor(acc.z, m, 64);
            acc.w += __shfl_xor(acc.w, m, 64);
        }
        if (g == 0) {
            float di = dinv[n];
            ushort4 h;
            h.x = f2b_rne(acc.x * di);
            h.y = f2b_rne(acc.y * di);
            h.z = f2b_rne(acc.z * di);
            h.w = f2b_rne(acc.w * di);
            *(ushort4*)&ghi[(size_t)n * 64 + t * 4] = h;
        }
    }
}

// ---- dense phase: D = relu([h|agg]@[Ws;Wn]+b); B streamed from L1/L2 ----
__device__ __forceinline__ void dense_phase(
    const unsigned short* __restrict__ Hhi, const unsigned short* __restrict__ Ghi,
    const unsigned short* __restrict__ Bthi, const unsigned short* __restrict__ Btlo,
    const float* __restrict__ b, unsigned short* __restrict__ Dhi,
    int N, int wid, int nw, int lane) {
    int m = lane & 15, quad = lane >> 4;
    int ngroups = (N + 15) >> 4;
    for (int gg = wid; gg < ngroups; gg += nw) {
        int n0 = gg << 4;
        int nr = n0 + m;
        if (nr > N - 1) nr = N - 1;
        const unsigned short* hrow = Hhi + (size_t)nr * 64 + quad * 8;
        const unsigned short* grow = Ghi + (size_t)nr * 64 + quad * 8;
        bfrag ah[4];
        ah[0] = *(const bfrag*)(hrow);
        ah[1] = *(const bfrag*)(hrow + 32);
        ah[2] = *(const bfrag*)(grow);
        ah[3] = *(const bfrag*)(grow + 32);
#pragma unroll
        for (int t = 0; t < 4; ++t) {
            float bl = b[t * 16 + m];
            ffrag acc = {bl, bl, bl, bl};
#pragma unroll
            for (int c = 0; c < 4; ++c) {
                bfrag bh = *(const bfrag*)(Bthi + (size_t)(t * 16 + m) * 128 + c * 32 + quad * 8);
                bfrag bw = *(const bfrag*)(Btlo + (size_t)(t * 16 + m) * 128 + c * 32 + quad * 8);
                acc = __builtin_amdgcn_mfma_f32_16x16x32_bf16(ah[c], bh, acc, 0, 0, 0);
                acc = __builtin_amdgcn_mfma_f32_16x16x32_bf16(ah[c], bw, acc, 0, 0, 0);
            }
#pragma unroll
            for (int r = 0; r < 4; ++r) {
                int node = n0 + quad * 4 + r;
                if (node < N)
                    Dhi[(size_t)node * 64 + t * 16 + m] = f2b_rne(fmaxf(acc[r], 0.f));
            }
        }
    }
}

// ---- last dense: fused layer-4 pre-transform (s,g from fp32 accs) ----
__device__ __forceinline__ void dense_last_phase(
    const unsigned short* __restrict__ Hhi, const unsigned short* __restrict__ Ghi,
    const unsigned short* __restrict__ Bthi, const unsigned short* __restrict__ Btlo,
    const float* __restrict__ b, const float* __restrict__ Ws4,
    const float* __restrict__ Wn4, float* __restrict__ sbuf,
    float* __restrict__ gbuf, int N, int wid, int nw, int lane) {
    int m = lane & 15, quad = lane >> 4;
    int ngroups = (N + 15) >> 4;
    for (int gg = wid; gg < ngroups; gg += nw) {
        int n0 = gg << 4;
        int nr = n0 + m;
        if (nr > N - 1) nr = N - 1;
        const unsigned short* hrow = Hhi + (size_t)nr * 64 + quad * 8;
        const unsigned short* grow = Ghi + (size_t)nr * 64 + quad * 8;
        bfrag ah[4];
        ah[0] = *(const bfrag*)(hrow);
        ah[1] = *(const bfrag*)(hrow + 32);
        ah[2] = *(const bfrag*)(grow);
        ah[3] = *(const bfrag*)(grow + 32);
        ffrag accs[4];
#pragma unroll
        for (int t = 0; t < 4; ++t) {
            float bl = b[t * 16 + m];
            ffrag acc = {bl, bl, bl, bl};
#pragma unroll
            for (int c = 0; c < 4; ++c) {
                bfrag bh = *(const bfrag*)(Bthi + (size_t)(t * 16 + m) * 128 + c * 32 + quad * 8);
                bfrag bw = *(const bfrag*)(Btlo + (size_t)(t * 16 + m) * 128 + c * 32 + quad * 8);
                acc = __builtin_amdgcn_mfma_f32_16x16x32_bf16(ah[c], bh, acc, 0, 0, 0);
                acc = __builtin_amdgcn_mfma_f32_16x16x32_bf16(ah[c], bw, acc, 0, 0, 0);
            }
            accs[t] = acc;
        }
        float w4s[4], w4n[4];
#pragma unroll
        for (int t = 0; t < 4; ++t) {
            w4s[t] = Ws4[t * 16 + m];
            w4n[t] = Wn4[t * 16 + m];
        }
#pragma unroll
        for (int r = 0; r < 4; ++r) {
            float ps = 0.f, pg = 0.f;
#pragma unroll
            for (int t = 0; t < 4; ++t) {
                float v = fmaxf(accs[t][r], 0.f);
                ps = fmaf(v, w4s[t], ps);
                pg = fmaf(v, w4n[t], pg);
            }
#pragma unroll
            for (int mask = 1; mask <= 8; mask <<= 1) {
                ps += __shfl_xor(ps, mask, 64);
                pg += __shfl_xor(pg, mask, 64);
            }
            int node = n0 + quad * 4 + r;
            if (m == 0 && node < N) {
                sbuf[node] = ps;
                gbuf[node] = pg;
            }
        }
    }
}

__global__ __launch_bounds__(256) void mega_kernel(
    const float4* __restrict__ x4, const int* __restrict__ ei,
    const float* __restrict__ Ws1, const float* __restrict__ Wn1, const float* __restrict__ b1,
    const float* __restrict__ Ws2, const float* __restrict__ Wn2, const float* __restrict__ b2,
    const float* __restrict__ Ws3, const float* __restrict__ Wn3, const float* __restrict__ b3,
    const float* __restrict__ Ws4, const float* __restrict__ Wn4, const float* __restrict__ b4,
    float* __restrict__ out,
    unsigned* __restrict__ bins, int* __restrict__ col,
    unsigned short* __restrict__ HhiA, unsigned short* __restrict__ HhiB,
    unsigned short* __restrict__ Ghi, unsigned short* __restrict__ Bth,
    unsigned short* __restrict__ Btl, float* __restrict__ dinv,
    float* __restrict__ sbuf, float* __restrict__ gbuf,
    int* __restrict__ off, int* __restrict__ offe,
    int* __restrict__ bktc, int* __restrict__ flag,
    int N, int E, int nbkt, int cap) {
    cg::grid_group grid = cg::this_grid();
    __shared__ int smem[2048];
    int tid = blockIdx.x * 256 + threadIdx.x;
    int nthr = gridDim.x * 256;
    int wid = tid >> 6;
    int nw = nthr >> 6;
    int lane = threadIdx.x & 63;
    int g = lane >> 4;
    int t16 = lane & 15;

    // ---- phase 0: prep (weights B^T hi/lo, x->bf16, bktc zero, flag) ----
    for (int i = tid; i < 3 * 8192; i += nthr) {
        int layer = i >> 13;
        int j = i & 8191;
        int n = j >> 7, k = j & 127;
        const float* Ws = layer == 0 ? Ws1 : (layer == 1 ? Ws2 : Ws3);
        const float* Wn = layer == 0 ? Wn1 : (layer == 1 ? Wn2 : Wn3);
        float v = (k < 64) ? Ws[k * 64 + n] : Wn[(k - 64) * 64 + n];
        unsigned short hi = f2b_rne(v);
        Bth[i] = hi;
        Btl[i] = f2b_rne(v - b2f(hi));
    }
    for (int i = tid; i < N * 16; i += nthr) {
        float4 v = x4[i];
        ushort4 h;
        h.x = f2b_rne(v.x); h.y = f2b_rne(v.y);
        h.z = f2b_rne(v.z); h.w = f2b_rne(v.w);
        ((ushort4*)HhiA)[i] = h;
    }
    for (int i = tid; i < nbkt; i += nthr) bktc[i] = 0;
    if (tid == 0) {
        int allz = 1;
        for (int i = 0; i < 32; ++i)
            if (ei[2 * i + 1] != 0) allz = 0;
        *flag = allz;
    }
    grid.sync();

    // ---- phase 1: binA (first min(grid,BINB) blocks) ----
    {
        int binb = min((int)gridDim.x, BINB);
        if ((int)blockIdx.x < binb) {
            int* cnt = smem;
            int* base = smem + 1024;
            int is64 = *flag;
            int chunksz = (E + binb - 1) / binb;
            int elo = blockIdx.x * chunksz;
            int ehi = min(E, elo + chunksz);
            if (elo < E) {
                for (int i = threadIdx.x; i < nbkt; i += 256) cnt[i] = 0;
                __syncthreads();
                for (int e = elo + (int)threadIdx.x; e < ehi; e += 256) {
                    int dst = load_idx32(ei, is64, (long long)E + e);
                    atomicAdd(&cnt[dst >> BKT_SHIFT], 1);
                }
                __syncthreads();
                for (int i = threadIdx.x; i < nbkt; i += 256) {
                    base[i] = atomicAdd(&bktc[i], cnt[i]);
                    cnt[i] = 0;
                }
                __syncthreads();
                for (int e = elo + (int)threadIdx.x; e < ehi; e += 256) {
                    int dst = load_idx32(ei, is64, (long long)E + e);
                    int src = load_idx32(ei, is64, e);
                    int b = dst >> BKT_SHIFT;
                    int r = atomicAdd(&cnt[b], 1);
                    bins[(size_t)b * cap + base[b] + r] =
                        ((unsigned)(dst & (BKT_NODES - 1)) << 24) | (unsigned)src;
                }
            }
        }
    }
    grid.sync();

    // ---- phase 2: bucketCSR (block per bucket, grid-stride) ----
    for (int b = blockIdx.x; b < nbkt; b += gridDim.x) {
        int* deg = smem;
        int* loc = smem + BKT_NODES;
        int* ssum = smem + 2 * BKT_NODES;
        int lo = b << BKT_SHIFT;
        int n = min(BKT_NODES, N - lo);
        int t = threadIdx.x;
        if (t < BKT_NODES) deg[t] = 0;
        __syncthreads();
        int cnt = bktc[b];
        const unsigned* bb = bins + (size_t)b * cap;
        for (int i = t; i < cnt; i += 256)
            atomicAdd(&deg[bb[i] >> 24], 1);
        __syncthreads();
        if (t < BKT_NODES) ssum[t] = deg[t];
        __syncthreads();
        for (int o = 1; o < BKT_NODES; o <<= 1) {
            int v = (t >= o && t < BKT_NODES) ? ssum[t - o] : 0;
            __syncthreads();
            if (t < BKT_NODES) ssum[t] += v;
            __syncthreads();
        }
        if (t < BKT_NODES) loc[t] = ssum[t] - deg[t];
        __syncthreads();
        int base = b * cap;
        if (t < n) {
            int d = deg[t];
            off[lo + t] = base + loc[t];
            offe[lo + t] = base + loc[t] + d;
            dinv[lo + t] = 1.0f / fmaxf((float)d, 1.0f);
        }
        __syncthreads();
        for (int i = t; i < cnt; i += 256) {
            unsigned p = bb[i];
            int pos = atomicAdd(&loc[p >> 24], 1);
            col[base + pos] = (int)(p & 0xFFFFFFu);
        }
        __syncthreads();
    }
    grid.sync();

    // ---- layer 1 ----
    gather_phase(HhiA, off, offe, col, dinv, Ghi, N, wid, nw, g, t16);
    grid.sync();
    dense_phase(HhiA, Ghi, Bth, Btl, b1, HhiB, N, wid, nw, lane);
    grid.sync();

    // ---- layer 2 ----
    gather_phase(HhiB, off, offe, col, dinv, Ghi, N, wid, nw, g, t16);
    grid.sync();
    dense_phase(HhiB, Ghi, Bth + 8192, Btl + 8192, b2, HhiA, N, wid, nw, lane);
    grid.sync();

    // ---- layer 3 + fused layer-4 pre-transform ----
    gather_phase(HhiA, off, offe, col, dinv, Ghi, N, wid, nw, g, t16);
    grid.sync();
    dense_last_phase(HhiA, Ghi, Bth + 16384, Btl + 16384, b3, Ws4, Wn4,
                     sbuf, gbuf, N, wid, nw, lane);
    grid.sync();

    // ---- phase 9: final (thread per node) ----
    for (int n = tid; n < N; n += nthr) {
        float a = 0.f;
        int e = off[n], end = offe[n];
        for (; e < end; ++e) a += gbuf[col[e]];
        float z = sbuf[n] + dinv[n] * a + b4[0];
        out[n] = 1.0f / (1.0f + expf(-z));
    }
}

static inline int cdiv(long long a, long long b) { return (int)((a + b - 1) / b); }

extern "C" void kernel_launch(void* const* d_in, const int* in_sizes, int n_in,
                              void* d_out, int out_size, void* d_ws, size_t ws_size,
                              hipStream_t stream) {
    const float* x   = (const float*)d_in[0];
    const int*   ei  = (const int*)d_in[1];
    const float* Ws1 = (const float*)d_in[2];
    const float* Wn1 = (const float*)d_in[3];
    const float* b1  = (const float*)d_in[4];
    const float* Ws2 = (const float*)d_in[5];
    const float* Wn2 = (const float*)d_in[6];
    const float* b2  = (const float*)d_in[7];
    const float* Ws3 = (const float*)d_in[8];
    const float* Wn3 = (const float*)d_in[9];
    const float* b3  = (const float*)d_in[10];
    const float* Ws4 = (const float*)d_in[11];
    const float* Wn4 = (const float*)d_in[12];
    const float* b4  = (const float*)d_in[13];
    float* out = (float*)d_out;

    int N = in_sizes[0] / 64;
    int E = in_sizes[1] / 2;
    int nbkt = cdiv(N, BKT_NODES);                  // <=1024 for N<=131072
    int cap  = E / nbkt + E / nbkt / 8 + 64;        // ~12.5% + 64 margin

    // workspace layout
    unsigned* bins = (unsigned*)d_ws;                    // nbkt*cap
    int* col = (int*)(bins + (size_t)nbkt * cap);        // nbkt*cap
    unsigned short* HhiA = (unsigned short*)(col + (size_t)nbkt * cap);  // N*64
    unsigned short* HhiB = HhiA + (size_t)N * 64;        // N*64
    unsigned short* Ghi  = HhiB + (size_t)N * 64;        // N*64
    unsigned short* Bth  = Ghi + (size_t)N * 64;         // 3*8192
    unsigned short* Btl  = Bth + 3 * 8192;               // 3*8192
    float* dinv = (float*)(Btl + 3 * 8192);              // N
    float* sbuf = dinv + N;                              // N
    float* gbuf = sbuf + N;                              // N
    int*   off  = (int*)(gbuf + N);                      // N
    int*   offe = off + N;                               // N
    int*   bktc = offe + N;                              // 1024
    int*   flag = bktc + 1024;                           // 1

    // cooperative grid sizing: co-resident blocks only
    int cus = 256, maxBlk = 4;
    hipDeviceGetAttribute(&cus, hipDeviceAttributeMultiprocessorCount, 0);
    hipOccupancyMaxActiveBlocksPerMultiprocessor(&maxBlk, (const void*)mega_kernel,
                                                 256, 0);
    if (maxBlk < 1) maxBlk = 1;
    int gridSz = cus * maxBlk;

    const float4* x4 = (const float4*)x;
    void* args[] = {
        (void*)&x4, (void*)&ei,
        (void*)&Ws1, (void*)&Wn1, (void*)&b1,
        (void*)&Ws2, (void*)&Wn2, (void*)&b2,
        (void*)&Ws3, (void*)&Wn3, (void*)&b3,
        (void*)&Ws4, (void*)&Wn4, (void*)&b4,
        (void*)&out,
        (void*)&bins, (void*)&col, (void*)&HhiA, (void*)&HhiB,
        (void*)&Ghi, (void*)&Bth, (void*)&Btl, (void*)&dinv,
        (void*)&sbuf, (void*)&gbuf, (void*)&off, (void*)&offe,
        (void*)&bktc, (void*)&flag,
        (void*)&N, (void*)&E, (void*)&nbkt, (void*)&cap,
    };
    hipLaunchCooperativeKernel((const void*)mega_kernel, dim3(gridSz), dim3(256),
                               args, 0, stream);
}